// Round 3
// baseline (532.538 us; speedup 1.0000x reference)
//
#include <hip/hip_runtime.h>
#include <math.h>

#define BB 16384
#define DD 4096
#define EE 64
#define TK 8

typedef __attribute__((ext_vector_type(8))) short s16x8;
typedef __attribute__((ext_vector_type(4))) float f32x4;

__device__ inline unsigned pack_hi2(float a, float b) {
    // two bf16 (truncated from fp32) packed into one u32: a -> low16, b -> high16
    return (__float_as_uint(a) >> 16) | (__float_as_uint(b) & 0xFFFF0000u);
}
__device__ inline float hi_part(float a) {
    return __uint_as_float(__float_as_uint(a) & 0xFFFF0000u);
}
__device__ inline void split_pack(const float4& v0, const float4& v1, uint4& h, uint4& l) {
    h.x = pack_hi2(v0.x, v0.y); h.y = pack_hi2(v0.z, v0.w);
    h.z = pack_hi2(v1.x, v1.y); h.w = pack_hi2(v1.z, v1.w);
    l.x = pack_hi2(v0.x - hi_part(v0.x), v0.y - hi_part(v0.y));
    l.y = pack_hi2(v0.z - hi_part(v0.z), v0.w - hi_part(v0.w));
    l.z = pack_hi2(v1.x - hi_part(v1.x), v1.y - hi_part(v1.y));
    l.w = pack_hi2(v1.z - hi_part(v1.z), v1.w - hi_part(v1.w));
}

// ---------------------------------------------------------------------------
// prep: convert [wg | wn] fp32 -> bf16 hi/lo in MFMA B-fragment order in ws.
// ws layout: [kchunk(64)][sub(2)][prec(2)][ntile(8)][lane(64)][16B]
//   lane = q*16 + (n&15), slot j = k&7, k_in_chunk = sub*32 + q*8 + j
// (verified correct in round 2)
// ---------------------------------------------------------------------------
__global__ __launch_bounds__(256, 1)
void prep_w(const float* __restrict__ wg, const float* __restrict__ wn,
            char* __restrict__ wsB)
{
    __shared__ float Wtmp[64 * 132];
    const int t  = threadIdx.x;
    const int kc = blockIdx.x;

#pragma unroll
    for (int i = 0; i < 8; ++i) {
        int fid = t + i * 256;
        int m   = fid >> 10;
        int id  = fid & 1023;
        int kk  = id >> 4;
        int n4  = id & 15;
        const float* src = (m ? wn : wg) + (size_t)(kc * 64 + kk) * EE + n4 * 4;
        float4 v = *(const float4*)src;
        *(float4*)&Wtmp[kk * 132 + m * 64 + n4 * 4] = v;
    }
    __syncthreads();

#pragma unroll
    for (int i = 0; i < 4; ++i) {
        int id  = t + i * 256;
        int sub = id >> 9;
        int nt  = (id >> 6) & 7;
        int ln  = id & 63;
        int n   = nt * 16 + (ln & 15);
        int k0  = sub * 32 + (ln >> 4) * 8;
        float f[8];
#pragma unroll
        for (int j = 0; j < 8; ++j) f[j] = Wtmp[(k0 + j) * 132 + n];
        uint4 h, l;
        h.x = pack_hi2(f[0], f[1]); h.y = pack_hi2(f[2], f[3]);
        h.z = pack_hi2(f[4], f[5]); h.w = pack_hi2(f[6], f[7]);
        l.x = pack_hi2(f[0] - hi_part(f[0]), f[1] - hi_part(f[1]));
        l.y = pack_hi2(f[2] - hi_part(f[2]), f[3] - hi_part(f[3]));
        l.z = pack_hi2(f[4] - hi_part(f[4]), f[5] - hi_part(f[5]));
        l.w = pack_hi2(f[6] - hi_part(f[6]), f[7] - hi_part(f[7]));
        size_t base = (size_t)kc * 32768;
        *(uint4*)(wsB + base + (size_t)(((sub * 2 + 0) * 8 + nt) * 64 + ln) * 16) = h;
        *(uint4*)(wsB + base + (size_t)(((sub * 2 + 1) * 8 + nt) * 64 + ln) * 16) = l;
    }
}

// ---------------------------------------------------------------------------
// main: 256 blocks x 256 threads (4 waves). Block = 64 rows x 128 cols, K=4096.
// Waves: (wm 0..1) x (wn 0..1); wave tile 32m x 64n; bf16x2 split (3 MFMAs).
// A: direct global->register, prefetched one chunk ahead (no LDS, no barrier dep).
// B: global_load_lds DMA, double-buffered, issued right after the barrier so
//    the vmcnt drain at the NEXT barrier finds it already landed.
// ---------------------------------------------------------------------------
__global__ __launch_bounds__(256, 1)
void moe_mfma(const float* __restrict__ x,
              const float* __restrict__ noise,
              const char* __restrict__ wsB,
              float* __restrict__ gates,
              float* __restrict__ load)
{
    __shared__ uint4 Bbuf[2][2048];   // 2 x 32 KB; [sub2][prec2][nt8][lane64]
    __shared__ float red[256];

    const int tid  = threadIdx.x;
    const int w    = tid >> 6;
    const int lane = tid & 63;
    const int wm   = w >> 1;          // rows wm*32 .. +31
    const int wnh  = w & 1;           // cols wnh*64 .. +63
    const int rb   = blockIdx.x * 64;

    const int m16 = lane & 15;
    const int q   = lane >> 4;

    // lane's A source: row rb + wm*32 + mt*16 + m16, k base q*8 (+ sub*32 + ch*64)
    const float* xbase = x + (size_t)(rb + wm * 32 + m16) * DD + q * 8;

    f32x4 acc[2][4];
#pragma unroll
    for (int mt = 0; mt < 2; ++mt)
#pragma unroll
        for (int nt = 0; nt < 4; ++nt) acc[mt][nt] = (f32x4){0.f, 0.f, 0.f, 0.f};

    auto issue_dma = [&](int ch, int b) {
        const char* gB = wsB + (size_t)ch * 32768;
#pragma unroll
        for (int i = 0; i < 8; ++i) {
            const int si = w * 8 + i;
            __builtin_amdgcn_global_load_lds(
                (const __attribute__((address_space(1))) unsigned int*)(gB + (size_t)si * 1024 + lane * 16),
                (__attribute__((address_space(3))) unsigned int*)&Bbuf[b][si * 64],
                16, 0, 0);
        }
    };
    auto load_a = [&](int ch, float4* xv) {
#pragma unroll
        for (int mt = 0; mt < 2; ++mt)
#pragma unroll
            for (int sub = 0; sub < 2; ++sub) {
                const float* p = xbase + (size_t)mt * 16 * DD + ch * 64 + sub * 32;
                xv[(mt * 2 + sub) * 2 + 0] = *(const float4*)p;
                xv[(mt * 2 + sub) * 2 + 1] = *(const float4*)(p + 4);
            }
    };
    auto compute = [&](int b, const float4* xv) {
#pragma unroll
        for (int mt = 0; mt < 2; ++mt)
#pragma unroll
            for (int sub = 0; sub < 2; ++sub) {
                uint4 h, l;
                split_pack(xv[(mt * 2 + sub) * 2 + 0], xv[(mt * 2 + sub) * 2 + 1], h, l);
                const s16x8 ah = __builtin_bit_cast(s16x8, h);
                const s16x8 al = __builtin_bit_cast(s16x8, l);
#pragma unroll
                for (int nt = 0; nt < 4; ++nt) {
                    const s16x8 bh = *(const s16x8*)&Bbuf[b][((sub * 2 + 0) * 8 + wnh * 4 + nt) * 64 + lane];
                    const s16x8 bl = *(const s16x8*)&Bbuf[b][((sub * 2 + 1) * 8 + wnh * 4 + nt) * 64 + lane];
                    acc[mt][nt] = __builtin_amdgcn_mfma_f32_16x16x32_bf16(ah, bh, acc[mt][nt], 0, 0, 0);
                    acc[mt][nt] = __builtin_amdgcn_mfma_f32_16x16x32_bf16(ah, bl, acc[mt][nt], 0, 0, 0);
                    acc[mt][nt] = __builtin_amdgcn_mfma_f32_16x16x32_bf16(al, bh, acc[mt][nt], 0, 0, 0);
                }
            }
    };

    float4 xva[8], xvb[8];
    issue_dma(0, 0);
    load_a(0, xva);

    for (int ch = 0; ch < 64; ch += 2) {
        __syncthreads();                      // drains DMA(ch)->buf0 + A(ch) (issued one chunk ago)
        issue_dma(ch + 1, 1);
        load_a(ch + 1, xvb);
        compute(0, xva);
        __syncthreads();
        if (ch + 2 < 64) {
            issue_dma(ch + 2, 0);
            load_a(ch + 2, xva);
        }
        compute(1, xvb);
    }

    // ---- epilogue: logits via LDS overlay on Bbuf ----
    __syncthreads();
    float* Ls = (float*)&Bbuf[0][0];          // 64 x 132 floats = 33792 B < 64 KB
    const int q4 = lane >> 4, cc = lane & 15;
#pragma unroll
    for (int mt = 0; mt < 2; ++mt)
#pragma unroll
        for (int nt = 0; nt < 4; ++nt)
#pragma unroll
            for (int r = 0; r < 4; ++r)
                Ls[(wm * 32 + mt * 16 + q4 * 4 + r) * 132 + wnh * 64 + nt * 16 + cc] = acc[mt][nt][r];
    __syncthreads();

    float loadAcc = 0.f;
    for (int rr = 0; rr < 16; ++rr) {
        const int row = w * 16 + rr;
        const float clean = Ls[row * 132 + lane];
        const float rawn  = Ls[row * 132 + 64 + lane];
        const float nz    = noise[(size_t)(rb + row) * EE + lane];

        const float sp = fmaxf(rawn, 0.f) + log1pf(expf(-fabsf(rawn)));
        const float sd = sp + 0.01f;
        const float noisy = clean + nz * sd;

        float m = noisy;
#pragma unroll
        for (int off = 32; off; off >>= 1) m = fmaxf(m, __shfl_xor(m, off));
        const float ex = expf(noisy - m);
        float s = ex;
#pragma unroll
        for (int off = 32; off; off >>= 1) s += __shfl_xor(s, off);
        const float p = ex / s;

        float cur = p;
        int selrank = -1;
        float v[9];
#pragma unroll
        for (int j = 0; j < 9; ++j) {
            float bv = cur;
            int   bi = lane;
#pragma unroll
            for (int off = 32; off; off >>= 1) {
                const float ov = __shfl_xor(bv, off);
                const int   oi = __shfl_xor(bi, off);
                if (ov > bv || (ov == bv && oi < bi)) { bv = ov; bi = oi; }
            }
            v[j] = bv;
            if (lane == bi) { cur = -1.f; if (j < TK) selrank = j; }
        }

        float denom = 0.f;
#pragma unroll
        for (int j = 0; j < TK; ++j) denom += expf(v[j] - v[0]);
        const float gate = (selrank >= 0) ? (expf(p - v[0]) / denom) : 0.f;
        gates[(size_t)(rb + row) * EE + lane] = gate;

        const float thr_in  = v[8];
        const float thr_out = v[7];
        const bool  is_in   = noisy > thr_in;
        const float a = (clean - (is_in ? thr_in : thr_out)) / sd;
        loadAcc += 0.5f * (1.f + erff(a * 0.70710678118654752f));
    }

    red[w * 64 + lane] = loadAcc;
    __syncthreads();
    if (tid < 64) {
        const float s = red[tid] + red[64 + tid] + red[128 + tid] + red[192 + tid];
        atomicAdd(&load[tid], s);
    }
}

extern "C" void kernel_launch(void* const* d_in, const int* in_sizes, int n_in,
                              void* d_out, int out_size, void* d_ws, size_t ws_size,
                              hipStream_t stream)
{
    const float* x     = (const float*)d_in[0];
    const float* wg    = (const float*)d_in[1];
    const float* wn    = (const float*)d_in[2];
    const float* noise = (const float*)d_in[3];
    float* gates = (float*)d_out;
    float* load  = (float*)d_out + (size_t)BB * EE;
    char*  wsB   = (char*)d_ws;   // 2 MB

    hipMemsetAsync(load, 0, EE * sizeof(float), stream);
    hipLaunchKernelGGL(prep_w, dim3(DD / 64), dim3(256), 0, stream, wg, wn, wsB);
    hipLaunchKernelGGL(moe_mfma, dim3(BB / 64), dim3(256), 0, stream,
                       x, noise, wsB, gates, load);
}

// Round 4
// 500.127 us; speedup vs baseline: 1.0648x; 1.0648x over previous
//
#include <hip/hip_runtime.h>
#include <math.h>

#define BB 16384
#define DD 4096
#define EE 64
#define TK 8
#define RT 32            // rows per block (grid = 512 -> 2 blocks/CU)

typedef __attribute__((ext_vector_type(8))) short s16x8;
typedef __attribute__((ext_vector_type(4))) float f32x4;

__device__ inline unsigned pack_hi2(float a, float b) {
    // two bf16 (truncated from fp32) packed into one u32: a -> low16, b -> high16
    return (__float_as_uint(a) >> 16) | (__float_as_uint(b) & 0xFFFF0000u);
}
__device__ inline float hi_part(float a) {
    return __uint_as_float(__float_as_uint(a) & 0xFFFF0000u);
}
__device__ inline void split_pack(const float4& v0, const float4& v1, uint4& h, uint4& l) {
    h.x = pack_hi2(v0.x, v0.y); h.y = pack_hi2(v0.z, v0.w);
    h.z = pack_hi2(v1.x, v1.y); h.w = pack_hi2(v1.z, v1.w);
    l.x = pack_hi2(v0.x - hi_part(v0.x), v0.y - hi_part(v0.y));
    l.y = pack_hi2(v0.z - hi_part(v0.z), v0.w - hi_part(v0.w));
    l.z = pack_hi2(v1.x - hi_part(v1.x), v1.y - hi_part(v1.y));
    l.w = pack_hi2(v1.z - hi_part(v1.z), v1.w - hi_part(v1.w));
}

// ---------------------------------------------------------------------------
// prep: convert [wg | wn] fp32 -> bf16 hi/lo in MFMA B-fragment order in ws.
// ws layout: [kchunk(64)][sub(2)][prec(2)][ntile(8)][lane(64)][16B]
//   lane = q*16 + (n&15), slot j = k&7, k_in_chunk = sub*32 + q*8 + j
// (verified correct rounds 2-3)
// ---------------------------------------------------------------------------
__global__ __launch_bounds__(256, 1)
void prep_w(const float* __restrict__ wg, const float* __restrict__ wn,
            char* __restrict__ wsB)
{
    __shared__ float Wtmp[64 * 132];
    const int t  = threadIdx.x;
    const int kc = blockIdx.x;

#pragma unroll
    for (int i = 0; i < 8; ++i) {
        int fid = t + i * 256;
        int m   = fid >> 10;
        int id  = fid & 1023;
        int kk  = id >> 4;
        int n4  = id & 15;
        const float* src = (m ? wn : wg) + (size_t)(kc * 64 + kk) * EE + n4 * 4;
        float4 v = *(const float4*)src;
        *(float4*)&Wtmp[kk * 132 + m * 64 + n4 * 4] = v;
    }
    __syncthreads();

#pragma unroll
    for (int i = 0; i < 4; ++i) {
        int id  = t + i * 256;
        int sub = id >> 9;
        int nt  = (id >> 6) & 7;
        int ln  = id & 63;
        int n   = nt * 16 + (ln & 15);
        int k0  = sub * 32 + (ln >> 4) * 8;
        float f[8];
#pragma unroll
        for (int j = 0; j < 8; ++j) f[j] = Wtmp[(k0 + j) * 132 + n];
        uint4 h, l;
        h.x = pack_hi2(f[0], f[1]); h.y = pack_hi2(f[2], f[3]);
        h.z = pack_hi2(f[4], f[5]); h.w = pack_hi2(f[6], f[7]);
        l.x = pack_hi2(f[0] - hi_part(f[0]), f[1] - hi_part(f[1]));
        l.y = pack_hi2(f[2] - hi_part(f[2]), f[3] - hi_part(f[3]));
        l.z = pack_hi2(f[4] - hi_part(f[4]), f[5] - hi_part(f[5]));
        l.w = pack_hi2(f[6] - hi_part(f[6]), f[7] - hi_part(f[7]));
        size_t base = (size_t)kc * 32768;
        *(uint4*)(wsB + base + (size_t)(((sub * 2 + 0) * 8 + nt) * 64 + ln) * 16) = h;
        *(uint4*)(wsB + base + (size_t)(((sub * 2 + 1) * 8 + nt) * 64 + ln) * 16) = l;
    }
}

// ---------------------------------------------------------------------------
// main: 512 blocks x 256 threads (4 waves) -> 2 independent blocks per CU.
// Block = 32 rows x 128 cols, K=4096. Waves (wm 0..1) x (wnh 0..1),
// wave tile 16m x 64n; bf16x2 split (3 MFMAs per frag pair).
// A: global->register, prefetched one chunk ahead (no barrier dependence).
// B: fragment-ordered global_load_lds DMA, double-buffered, 1 barrier/chunk.
// Two co-resident blocks hide each other's barrier drains.
// ---------------------------------------------------------------------------
__global__ __launch_bounds__(256, 1)
void moe_mfma(const float* __restrict__ x,
              const float* __restrict__ noise,
              const char* __restrict__ wsB,
              float* __restrict__ gates,
              float* __restrict__ load)
{
    __shared__ uint4 Bbuf[2][2048];   // 2 x 32 KB; [sub2][prec2][nt8][lane64]
    __shared__ float red[256];

    const int tid  = threadIdx.x;
    const int w    = tid >> 6;
    const int lane = tid & 63;
    const int wm   = w >> 1;          // rows wm*16 .. +15
    const int wnh  = w & 1;           // cols wnh*64 .. +63
    const int rb   = blockIdx.x * RT;

    const int m16 = lane & 15;
    const int q   = lane >> 4;

    // lane's A source: row rb + wm*16 + m16, k base q*8 (+ sub*32 + ch*64)
    const float* xbase = x + (size_t)(rb + wm * 16 + m16) * DD + q * 8;

    f32x4 acc[4];
#pragma unroll
    for (int nt = 0; nt < 4; ++nt) acc[nt] = (f32x4){0.f, 0.f, 0.f, 0.f};

    auto issue_dma = [&](int ch, int b) {
        const char* gB = wsB + (size_t)ch * 32768;
#pragma unroll
        for (int i = 0; i < 8; ++i) {
            const int si = w * 8 + i;
            __builtin_amdgcn_global_load_lds(
                (const __attribute__((address_space(1))) unsigned int*)(gB + (size_t)si * 1024 + lane * 16),
                (__attribute__((address_space(3))) unsigned int*)&Bbuf[b][si * 64],
                16, 0, 0);
        }
    };
    auto load_a = [&](int ch, float4* xv) {
#pragma unroll
        for (int sub = 0; sub < 2; ++sub) {
            const float* p = xbase + ch * 64 + sub * 32;
            xv[sub * 2 + 0] = *(const float4*)p;
            xv[sub * 2 + 1] = *(const float4*)(p + 4);
        }
    };
    auto compute = [&](int b, const float4* xv) {
#pragma unroll
        for (int sub = 0; sub < 2; ++sub) {
            uint4 h, l;
            split_pack(xv[sub * 2 + 0], xv[sub * 2 + 1], h, l);
            const s16x8 ah = __builtin_bit_cast(s16x8, h);
            const s16x8 al = __builtin_bit_cast(s16x8, l);
#pragma unroll
            for (int nt = 0; nt < 4; ++nt) {
                const s16x8 bh = *(const s16x8*)&Bbuf[b][((sub * 2 + 0) * 8 + wnh * 4 + nt) * 64 + lane];
                const s16x8 bl = *(const s16x8*)&Bbuf[b][((sub * 2 + 1) * 8 + wnh * 4 + nt) * 64 + lane];
                acc[nt] = __builtin_amdgcn_mfma_f32_16x16x32_bf16(ah, bh, acc[nt], 0, 0, 0);
                acc[nt] = __builtin_amdgcn_mfma_f32_16x16x32_bf16(ah, bl, acc[nt], 0, 0, 0);
                acc[nt] = __builtin_amdgcn_mfma_f32_16x16x32_bf16(al, bh, acc[nt], 0, 0, 0);
            }
        }
    };

    float4 xva[4], xvb[4];
    issue_dma(0, 0);
    load_a(0, xva);

    for (int ch = 0; ch < 64; ch += 2) {
        __syncthreads();                      // DMA(ch)->buf0 landed; buf1 free
        issue_dma(ch + 1, 1);
        load_a(ch + 1, xvb);
        compute(0, xva);
        __syncthreads();                      // DMA(ch+1)->buf1 landed; buf0 free
        if (ch + 2 < 64) {
            issue_dma(ch + 2, 0);
            load_a(ch + 2, xva);
        }
        compute(1, xvb);
    }

    // ---- epilogue: logits via LDS overlay on Bbuf ----
    __syncthreads();
    float* Ls = (float*)&Bbuf[0][0];          // 32 x 132 floats = 16896 B
    const int q4 = lane >> 4, cc = lane & 15;
#pragma unroll
    for (int nt = 0; nt < 4; ++nt)
#pragma unroll
        for (int r = 0; r < 4; ++r)
            Ls[(wm * 16 + q4 * 4 + r) * 132 + wnh * 64 + nt * 16 + cc] = acc[nt][r];
    __syncthreads();

    float loadAcc = 0.f;
    for (int rr = 0; rr < 8; ++rr) {
        const int row = w * 8 + rr;
        const float clean = Ls[row * 132 + lane];
        const float rawn  = Ls[row * 132 + 64 + lane];
        const float nz    = noise[(size_t)(rb + row) * EE + lane];

        const float sp = fmaxf(rawn, 0.f) + log1pf(expf(-fabsf(rawn)));
        const float sd = sp + 0.01f;
        const float noisy = clean + nz * sd;

        float m = noisy;
#pragma unroll
        for (int off = 32; off; off >>= 1) m = fmaxf(m, __shfl_xor(m, off));
        const float ex = expf(noisy - m);
        float s = ex;
#pragma unroll
        for (int off = 32; off; off >>= 1) s += __shfl_xor(s, off);
        const float p = ex / s;

        float cur = p;
        int selrank = -1;
        float v[9];
#pragma unroll
        for (int j = 0; j < 9; ++j) {
            float bv = cur;
            int   bi = lane;
#pragma unroll
            for (int off = 32; off; off >>= 1) {
                const float ov = __shfl_xor(bv, off);
                const int   oi = __shfl_xor(bi, off);
                if (ov > bv || (ov == bv && oi < bi)) { bv = ov; bi = oi; }
            }
            v[j] = bv;
            if (lane == bi) { cur = -1.f; if (j < TK) selrank = j; }
        }

        float denom = 0.f;
#pragma unroll
        for (int j = 0; j < TK; ++j) denom += expf(v[j] - v[0]);
        const float gate = (selrank >= 0) ? (expf(p - v[0]) / denom) : 0.f;
        gates[(size_t)(rb + row) * EE + lane] = gate;

        const float thr_in  = v[8];
        const float thr_out = v[7];
        const bool  is_in   = noisy > thr_in;
        const float a = (clean - (is_in ? thr_in : thr_out)) / sd;
        loadAcc += 0.5f * (1.f + erff(a * 0.70710678118654752f));
    }

    red[w * 64 + lane] = loadAcc;
    __syncthreads();
    if (tid < 64) {
        const float s = red[tid] + red[64 + tid] + red[128 + tid] + red[192 + tid];
        atomicAdd(&load[tid], s);
    }
}

extern "C" void kernel_launch(void* const* d_in, const int* in_sizes, int n_in,
                              void* d_out, int out_size, void* d_ws, size_t ws_size,
                              hipStream_t stream)
{
    const float* x     = (const float*)d_in[0];
    const float* wg    = (const float*)d_in[1];
    const float* wn    = (const float*)d_in[2];
    const float* noise = (const float*)d_in[3];
    float* gates = (float*)d_out;
    float* load  = (float*)d_out + (size_t)BB * EE;
    char*  wsB   = (char*)d_ws;   // 2 MB

    hipMemsetAsync(load, 0, EE * sizeof(float), stream);
    hipLaunchKernelGGL(prep_w, dim3(DD / 64), dim3(256), 0, stream, wg, wn, wsB);
    hipLaunchKernelGGL(moe_mfma, dim3(BB / RT), dim3(256), 0, stream,
                       x, noise, wsB, gates, load);
}

// Round 5
// 497.840 us; speedup vs baseline: 1.0697x; 1.0046x over previous
//
#include <hip/hip_runtime.h>
#include <math.h>

#define BB 16384
#define DD 4096
#define EE 64
#define TK 8
#define RT 32            // rows per block; grid = 512

typedef __attribute__((ext_vector_type(8))) short s16x8;
typedef __attribute__((ext_vector_type(4))) float f32x4;

__device__ inline unsigned pack_hi2(float a, float b) {
    return (__float_as_uint(a) >> 16) | (__float_as_uint(b) & 0xFFFF0000u);
}
__device__ inline float hi_part(float a) {
    return __uint_as_float(__float_as_uint(a) & 0xFFFF0000u);
}
__device__ inline void split_pack(const float4& v0, const float4& v1, uint4& h, uint4& l) {
    h.x = pack_hi2(v0.x, v0.y); h.y = pack_hi2(v0.z, v0.w);
    h.z = pack_hi2(v1.x, v1.y); h.w = pack_hi2(v1.z, v1.w);
    l.x = pack_hi2(v0.x - hi_part(v0.x), v0.y - hi_part(v0.y));
    l.y = pack_hi2(v0.z - hi_part(v0.z), v0.w - hi_part(v0.w));
    l.z = pack_hi2(v1.x - hi_part(v1.x), v1.y - hi_part(v1.y));
    l.w = pack_hi2(v1.z - hi_part(v1.z), v1.w - hi_part(v1.w));
}

// ---------------------------------------------------------------------------
// prep: [wg | wn] fp32 -> bf16 hi/lo in MFMA B-fragment order (verified r2-4).
// ws layout: [kchunk(64)][sub(2)][prec(2)][ntile(8)][lane(64)][16B]
// ---------------------------------------------------------------------------
__global__ __launch_bounds__(256, 1)
void prep_w(const float* __restrict__ wg, const float* __restrict__ wn,
            char* __restrict__ wsB)
{
    __shared__ float Wtmp[64 * 132];
    const int t  = threadIdx.x;
    const int kc = blockIdx.x;

#pragma unroll
    for (int i = 0; i < 8; ++i) {
        int fid = t + i * 256;
        int m   = fid >> 10;
        int id  = fid & 1023;
        int kk  = id >> 4;
        int n4  = id & 15;
        const float* src = (m ? wn : wg) + (size_t)(kc * 64 + kk) * EE + n4 * 4;
        float4 v = *(const float4*)src;
        *(float4*)&Wtmp[kk * 132 + m * 64 + n4 * 4] = v;
    }
    __syncthreads();

#pragma unroll
    for (int i = 0; i < 4; ++i) {
        int id  = t + i * 256;
        int sub = id >> 9;
        int nt  = (id >> 6) & 7;
        int ln  = id & 63;
        int n   = nt * 16 + (ln & 15);
        int k0  = sub * 32 + (ln >> 4) * 8;
        float f[8];
#pragma unroll
        for (int j = 0; j < 8; ++j) f[j] = Wtmp[(k0 + j) * 132 + n];
        uint4 h, l;
        h.x = pack_hi2(f[0], f[1]); h.y = pack_hi2(f[2], f[3]);
        h.z = pack_hi2(f[4], f[5]); h.w = pack_hi2(f[6], f[7]);
        l.x = pack_hi2(f[0] - hi_part(f[0]), f[1] - hi_part(f[1]));
        l.y = pack_hi2(f[2] - hi_part(f[2]), f[3] - hi_part(f[3]));
        l.z = pack_hi2(f[4] - hi_part(f[4]), f[5] - hi_part(f[5]));
        l.w = pack_hi2(f[6] - hi_part(f[6]), f[7] - hi_part(f[7]));
        size_t base = (size_t)kc * 32768;
        *(uint4*)(wsB + base + (size_t)(((sub * 2 + 0) * 8 + nt) * 64 + ln) * 16) = h;
        *(uint4*)(wsB + base + (size_t)(((sub * 2 + 1) * 8 + nt) * 64 + ln) * 16) = l;
    }
}

// ---------------------------------------------------------------------------
// main: 512 blocks x 256 threads. Block = 32 rows x 128 cols x full K.
// 4 waves = (nh 0..1) x (ks 0..1): wave tile 32m x 64n over K-half 2048.
// NO LDS, NO BARRIERS in the K-loop: A and B both global->register with
// register double-buffering; compiler emits fine-grained vmcnt per use.
// K-halves combined once at the end via a 17 KB LDS tile (2 barriers total),
// then the fused epilogue (verified r1-4) runs on the combined logits.
// ---------------------------------------------------------------------------
__global__ __launch_bounds__(256, 2)
void moe_mfma(const float* __restrict__ x,
              const float* __restrict__ noise,
              const char* __restrict__ wsB,
              float* __restrict__ gates,
              float* __restrict__ load)
{
    __shared__ float Ls[RT * 132];   // 16896 B combined-logits tile
    __shared__ float red[256];

    const int tid  = threadIdx.x;
    const int w    = tid >> 6;
    const int lane = tid & 63;
    const int nh   = w & 1;          // n-half: cols nh*64 .. +63
    const int ks   = w >> 1;         // K-half: k in [ks*2048, ks*2048+2048)
    const int rb   = blockIdx.x * RT;

    const int m16 = lane & 15;
    const int q   = lane >> 4;

    // A row pointers for this lane (mt=0: rows rb+m16, mt=1: rows rb+16+m16)
    const float* xr0 = x + (size_t)(rb + m16) * DD + ks * 2048 + q * 8;
    const float* xr1 = xr0 + (size_t)16 * DD;
    // B fragment base for this wave's n-half / K-half (uint4 units)
    const uint4* bbase = (const uint4*)wsB + (size_t)ks * 32 * 2048 + nh * 4 * 64 + lane;

    f32x4 acc[2][4];
#pragma unroll
    for (int mt = 0; mt < 2; ++mt)
#pragma unroll
        for (int nt = 0; nt < 4; ++nt) acc[mt][nt] = (f32x4){0.f, 0.f, 0.f, 0.f};

    // a[(mt*2+sub)*2 + {0,1}] : 8 float4
    auto load_A = [&](int ch, float4* a) {
#pragma unroll
        for (int mt = 0; mt < 2; ++mt)
#pragma unroll
            for (int sub = 0; sub < 2; ++sub) {
                const float* p = (mt ? xr1 : xr0) + ch * 64 + sub * 32;
                a[(mt * 2 + sub) * 2 + 0] = *(const float4*)p;
                a[(mt * 2 + sub) * 2 + 1] = *(const float4*)(p + 4);
            }
    };
    // b[prec*4 + nt] : 8 uint4 for one sub (32-k slice)
    auto load_B = [&](int ch, int sub, uint4* b) {
        const uint4* p = bbase + (size_t)ch * 2048;
#pragma unroll
        for (int prec = 0; prec < 2; ++prec)
#pragma unroll
            for (int nt = 0; nt < 4; ++nt)
                b[prec * 4 + nt] = p[((sub * 2 + prec) * 8 + nt) * 64];
    };
    auto compute_sub = [&](const float4* a, int sub, const uint4* b) {
#pragma unroll
        for (int mt = 0; mt < 2; ++mt) {
            uint4 h, l;
            split_pack(a[(mt * 2 + sub) * 2 + 0], a[(mt * 2 + sub) * 2 + 1], h, l);
            const s16x8 ah = __builtin_bit_cast(s16x8, h);
            const s16x8 al = __builtin_bit_cast(s16x8, l);
#pragma unroll
            for (int nt = 0; nt < 4; ++nt) {
                const s16x8 bh = __builtin_bit_cast(s16x8, b[nt]);
                const s16x8 bl = __builtin_bit_cast(s16x8, b[4 + nt]);
                acc[mt][nt] = __builtin_amdgcn_mfma_f32_16x16x32_bf16(ah, bh, acc[mt][nt], 0, 0, 0);
                acc[mt][nt] = __builtin_amdgcn_mfma_f32_16x16x32_bf16(ah, bl, acc[mt][nt], 0, 0, 0);
                acc[mt][nt] = __builtin_amdgcn_mfma_f32_16x16x32_bf16(al, bh, acc[mt][nt], 0, 0, 0);
            }
        }
    };

    float4 A0[8], A1[8];
    uint4  B0[8], B1[8];
    load_A(0, A0);
    load_B(0, 0, B0);
    load_B(0, 1, B1);

    for (int ch = 0; ch < 32; ch += 2) {
        // iter ch : consumes A0, B0(sub0), B1(sub1)
        load_A(ch + 1, A1);
        compute_sub(A0, 0, B0);
        load_B(ch + 1, 0, B0);
        compute_sub(A0, 1, B1);
        load_B(ch + 1, 1, B1);
        // iter ch+1 : consumes A1, refreshed B0/B1
        const int nx = (ch + 2 < 32) ? ch + 2 : 31;   // clamped redundant prefetch on last iter
        load_A(nx, A0);
        compute_sub(A1, 0, B0);
        load_B(nx, 0, B0);
        compute_sub(A1, 1, B1);
        load_B(nx, 1, B1);
    }

    // ---- combine K-halves in LDS (the only barriers in the kernel) ----
    const int q4 = lane >> 4, cc = lane & 15;
    if (ks == 0) {
#pragma unroll
        for (int mt = 0; mt < 2; ++mt)
#pragma unroll
            for (int nt = 0; nt < 4; ++nt)
#pragma unroll
                for (int r = 0; r < 4; ++r)
                    Ls[(mt * 16 + q4 * 4 + r) * 132 + nh * 64 + nt * 16 + cc] = acc[mt][nt][r];
    }
    __syncthreads();
    if (ks == 1) {
#pragma unroll
        for (int mt = 0; mt < 2; ++mt)
#pragma unroll
            for (int nt = 0; nt < 4; ++nt)
#pragma unroll
                for (int r = 0; r < 4; ++r)
                    Ls[(mt * 16 + q4 * 4 + r) * 132 + nh * 64 + nt * 16 + cc] += acc[mt][nt][r];
    }
    __syncthreads();

    // ---- fused epilogue (verified r1-4): wave-per-row, lane = expert ----
    float loadAcc = 0.f;
    for (int rr = 0; rr < 8; ++rr) {
        const int row = w * 8 + rr;
        const float clean = Ls[row * 132 + lane];
        const float rawn  = Ls[row * 132 + 64 + lane];
        const float nz    = noise[(size_t)(rb + row) * EE + lane];

        const float sp = fmaxf(rawn, 0.f) + log1pf(expf(-fabsf(rawn)));
        const float sd = sp + 0.01f;
        const float noisy = clean + nz * sd;

        float m = noisy;
#pragma unroll
        for (int off = 32; off; off >>= 1) m = fmaxf(m, __shfl_xor(m, off));
        const float ex = expf(noisy - m);
        float s = ex;
#pragma unroll
        for (int off = 32; off; off >>= 1) s += __shfl_xor(s, off);
        const float p = ex / s;

        float cur = p;
        int selrank = -1;
        float v[9];
#pragma unroll
        for (int j = 0; j < 9; ++j) {
            float bv = cur;
            int   bi = lane;
#pragma unroll
            for (int off = 32; off; off >>= 1) {
                const float ov = __shfl_xor(bv, off);
                const int   oi = __shfl_xor(bi, off);
                if (ov > bv || (ov == bv && oi < bi)) { bv = ov; bi = oi; }
            }
            v[j] = bv;
            if (lane == bi) { cur = -1.f; if (j < TK) selrank = j; }
        }

        float denom = 0.f;
#pragma unroll
        for (int j = 0; j < TK; ++j) denom += expf(v[j] - v[0]);
        const float gate = (selrank >= 0) ? (expf(p - v[0]) / denom) : 0.f;
        gates[(size_t)(rb + row) * EE + lane] = gate;

        const float thr_in  = v[8];
        const float thr_out = v[7];
        const bool  is_in   = noisy > thr_in;
        const float a = (clean - (is_in ? thr_in : thr_out)) / sd;
        loadAcc += 0.5f * (1.f + erff(a * 0.70710678118654752f));
    }

    red[w * 64 + lane] = loadAcc;
    __syncthreads();
    if (tid < 64) {
        const float s = red[tid] + red[64 + tid] + red[128 + tid] + red[192 + tid];
        atomicAdd(&load[tid], s);
    }
}

extern "C" void kernel_launch(void* const* d_in, const int* in_sizes, int n_in,
                              void* d_out, int out_size, void* d_ws, size_t ws_size,
                              hipStream_t stream)
{
    const float* x     = (const float*)d_in[0];
    const float* wg    = (const float*)d_in[1];
    const float* wn    = (const float*)d_in[2];
    const float* noise = (const float*)d_in[3];
    float* gates = (float*)d_out;
    float* load  = (float*)d_out + (size_t)BB * EE;
    char*  wsB   = (char*)d_ws;   // 2 MB

    hipMemsetAsync(load, 0, EE * sizeof(float), stream);
    hipLaunchKernelGGL(prep_w, dim3(DD / 64), dim3(256), 0, stream, wg, wn, wsB);
    hipLaunchKernelGGL(moe_mfma, dim3(BB / RT), dim3(256), 0, stream,
                       x, noise, wsB, gates, load);
}

// Round 6
// 464.858 us; speedup vs baseline: 1.1456x; 1.0710x over previous
//
#include <hip/hip_runtime.h>
#include <math.h>

#define BB 16384
#define DD 4096
#define EE 64
#define TK 8
#define RT 32            // rows per block; grid = 512

typedef __attribute__((ext_vector_type(8))) short s16x8;
typedef __attribute__((ext_vector_type(4))) float f32x4;

__device__ inline unsigned pack_hi2(float a, float b) {
    return (__float_as_uint(a) >> 16) | (__float_as_uint(b) & 0xFFFF0000u);
}
__device__ inline float hi_part(float a) {
    return __uint_as_float(__float_as_uint(a) & 0xFFFF0000u);
}
__device__ inline void split_pack(const float4& v0, const float4& v1, uint4& h, uint4& l) {
    h.x = pack_hi2(v0.x, v0.y); h.y = pack_hi2(v0.z, v0.w);
    h.z = pack_hi2(v1.x, v1.y); h.w = pack_hi2(v1.z, v1.w);
    l.x = pack_hi2(v0.x - hi_part(v0.x), v0.y - hi_part(v0.y));
    l.y = pack_hi2(v0.z - hi_part(v0.z), v0.w - hi_part(v0.w));
    l.z = pack_hi2(v1.x - hi_part(v1.x), v1.y - hi_part(v1.y));
    l.w = pack_hi2(v1.z - hi_part(v1.z), v1.w - hi_part(v1.w));
}

// ---------------------------------------------------------------------------
// prep: [wg | wn] fp32 -> bf16 hi/lo in MFMA B-fragment order (verified r2-5).
// ws layout: [kchunk(64)][sub(2)][prec(2)][ntile(8)][lane(64)][16B]
// ---------------------------------------------------------------------------
__global__ __launch_bounds__(256, 1)
void prep_w(const float* __restrict__ wg, const float* __restrict__ wn,
            char* __restrict__ wsB)
{
    __shared__ float Wtmp[64 * 132];
    const int t  = threadIdx.x;
    const int kc = blockIdx.x;

#pragma unroll
    for (int i = 0; i < 8; ++i) {
        int fid = t + i * 256;
        int m   = fid >> 10;
        int id  = fid & 1023;
        int kk  = id >> 4;
        int n4  = id & 15;
        const float* src = (m ? wn : wg) + (size_t)(kc * 64 + kk) * EE + n4 * 4;
        float4 v = *(const float4*)src;
        *(float4*)&Wtmp[kk * 132 + m * 64 + n4 * 4] = v;
    }
    __syncthreads();

#pragma unroll
    for (int i = 0; i < 4; ++i) {
        int id  = t + i * 256;
        int sub = id >> 9;
        int nt  = (id >> 6) & 7;
        int ln  = id & 63;
        int n   = nt * 16 + (ln & 15);
        int k0  = sub * 32 + (ln >> 4) * 8;
        float f[8];
#pragma unroll
        for (int j = 0; j < 8; ++j) f[j] = Wtmp[(k0 + j) * 132 + n];
        uint4 h, l;
        h.x = pack_hi2(f[0], f[1]); h.y = pack_hi2(f[2], f[3]);
        h.z = pack_hi2(f[4], f[5]); h.w = pack_hi2(f[6], f[7]);
        l.x = pack_hi2(f[0] - hi_part(f[0]), f[1] - hi_part(f[1]));
        l.y = pack_hi2(f[2] - hi_part(f[2]), f[3] - hi_part(f[3]));
        l.z = pack_hi2(f[4] - hi_part(f[4]), f[5] - hi_part(f[5]));
        l.w = pack_hi2(f[6] - hi_part(f[6]), f[7] - hi_part(f[7]));
        size_t base = (size_t)kc * 32768;
        *(uint4*)(wsB + base + (size_t)(((sub * 2 + 0) * 8 + nt) * 64 + ln) * 16) = h;
        *(uint4*)(wsB + base + (size_t)(((sub * 2 + 1) * 8 + nt) * 64 + ln) * 16) = l;
    }
}

// ---------------------------------------------------------------------------
// main: 512 blocks x 256 threads. Block = 32 rows x 128 cols x full K.
// 4 waves = (nh 0..1) x (ks 0..1): wave tile 32m x 64n over K-half 2048.
// No LDS/barriers in K-loop. Register double-buffered A (HBM stream, one
// chunk ahead) and B (L2 stream, rotated per sub). sched_barrier(0) after
// each load-issue region pins batched issue so the allocator must keep the
// prefetch buffers live (r5 failure: compiler sank loads, VGPR=68, serial
// per-wave latency chain ~15K cyc/chunk).
// ---------------------------------------------------------------------------
__global__ __launch_bounds__(256, 2)
void moe_mfma(const float* __restrict__ x,
              const float* __restrict__ noise,
              const char* __restrict__ wsB,
              float* __restrict__ gates,
              float* __restrict__ load)
{
    __shared__ float Ls[RT * 132];   // 16896 B combined-logits tile
    __shared__ float red[256];

    const int tid  = threadIdx.x;
    const int w    = tid >> 6;
    const int lane = tid & 63;
    const int nh   = w & 1;          // n-half: cols nh*64 .. +63
    const int ks   = w >> 1;         // K-half: k in [ks*2048, ks*2048+2048)
    const int rb   = blockIdx.x * RT;

    const int m16 = lane & 15;
    const int q   = lane >> 4;

    const float* xr0 = x + (size_t)(rb + m16) * DD + ks * 2048 + q * 8;
    const float* xr1 = xr0 + (size_t)16 * DD;
    const uint4* bbase = (const uint4*)wsB + (size_t)ks * 32 * 2048 + nh * 4 * 64 + lane;

    f32x4 acc[2][4];
#pragma unroll
    for (int mt = 0; mt < 2; ++mt)
#pragma unroll
        for (int nt = 0; nt < 4; ++nt) acc[mt][nt] = (f32x4){0.f, 0.f, 0.f, 0.f};

    auto load_A = [&](int ch, float4* a) {
#pragma unroll
        for (int mt = 0; mt < 2; ++mt)
#pragma unroll
            for (int sub = 0; sub < 2; ++sub) {
                const float* p = (mt ? xr1 : xr0) + ch * 64 + sub * 32;
                a[(mt * 2 + sub) * 2 + 0] = *(const float4*)p;
                a[(mt * 2 + sub) * 2 + 1] = *(const float4*)(p + 4);
            }
    };
    auto load_B = [&](int ch, int sub, uint4* b) {
        const uint4* p = bbase + (size_t)ch * 2048;
#pragma unroll
        for (int prec = 0; prec < 2; ++prec)
#pragma unroll
            for (int nt = 0; nt < 4; ++nt)
                b[prec * 4 + nt] = p[((sub * 2 + prec) * 8 + nt) * 64];
    };
    auto compute_sub = [&](const float4* a, int sub, const uint4* b) {
#pragma unroll
        for (int mt = 0; mt < 2; ++mt) {
            uint4 h, l;
            split_pack(a[(mt * 2 + sub) * 2 + 0], a[(mt * 2 + sub) * 2 + 1], h, l);
            const s16x8 ah = __builtin_bit_cast(s16x8, h);
            const s16x8 al = __builtin_bit_cast(s16x8, l);
#pragma unroll
            for (int nt = 0; nt < 4; ++nt) {
                const s16x8 bh = __builtin_bit_cast(s16x8, b[nt]);
                const s16x8 bl = __builtin_bit_cast(s16x8, b[4 + nt]);
                acc[mt][nt] = __builtin_amdgcn_mfma_f32_16x16x32_bf16(ah, bh, acc[mt][nt], 0, 0, 0);
                acc[mt][nt] = __builtin_amdgcn_mfma_f32_16x16x32_bf16(ah, bl, acc[mt][nt], 0, 0, 0);
                acc[mt][nt] = __builtin_amdgcn_mfma_f32_16x16x32_bf16(al, bh, acc[mt][nt], 0, 0, 0);
            }
        }
    };

    float4 A0[8], A1[8];
    uint4  B0[8], B1[8];
    load_A(0, A0);
    load_B(0, 0, B0);
    load_B(0, 1, B1);
    __builtin_amdgcn_sched_barrier(0);

    for (int ch = 0; ch < 32; ch += 2) {
        // ---- chunk ch : consumes A0, B0(sub0), B1(sub1) ----
        load_A(ch + 1, A1);                       // HBM prefetch, 1 chunk ahead
        __builtin_amdgcn_sched_barrier(0);        // pin: issue before compute
        compute_sub(A0, 0, B0);
        load_B(ch + 1, 0, B0);                    // L2 refill, 1 chunk ahead
        __builtin_amdgcn_sched_barrier(0);
        compute_sub(A0, 1, B1);
        load_B(ch + 1, 1, B1);
        __builtin_amdgcn_sched_barrier(0);

        // ---- chunk ch+1 : consumes A1, refreshed B0/B1 ----
        const int nx = (ch + 2 < 32) ? ch + 2 : 31;   // clamped redundant prefetch
        load_A(nx, A0);
        __builtin_amdgcn_sched_barrier(0);
        compute_sub(A1, 0, B0);
        load_B(nx, 0, B0);
        __builtin_amdgcn_sched_barrier(0);
        compute_sub(A1, 1, B1);
        load_B(nx, 1, B1);
        __builtin_amdgcn_sched_barrier(0);
    }

    // ---- combine K-halves in LDS (the only barriers in the kernel) ----
    const int q4 = lane >> 4, cc = lane & 15;
    if (ks == 0) {
#pragma unroll
        for (int mt = 0; mt < 2; ++mt)
#pragma unroll
            for (int nt = 0; nt < 4; ++nt)
#pragma unroll
                for (int r = 0; r < 4; ++r)
                    Ls[(mt * 16 + q4 * 4 + r) * 132 + nh * 64 + nt * 16 + cc] = acc[mt][nt][r];
    }
    __syncthreads();
    if (ks == 1) {
#pragma unroll
        for (int mt = 0; mt < 2; ++mt)
#pragma unroll
            for (int nt = 0; nt < 4; ++nt)
#pragma unroll
                for (int r = 0; r < 4; ++r)
                    Ls[(mt * 16 + q4 * 4 + r) * 132 + nh * 64 + nt * 16 + cc] += acc[mt][nt][r];
    }
    __syncthreads();

    // ---- fused epilogue (verified r1-5): wave-per-row, lane = expert ----
    float loadAcc = 0.f;
    for (int rr = 0; rr < 8; ++rr) {
        const int row = w * 8 + rr;
        const float clean = Ls[row * 132 + lane];
        const float rawn  = Ls[row * 132 + 64 + lane];
        const float nz    = noise[(size_t)(rb + row) * EE + lane];

        const float sp = fmaxf(rawn, 0.f) + log1pf(expf(-fabsf(rawn)));
        const float sd = sp + 0.01f;
        const float noisy = clean + nz * sd;

        float m = noisy;
#pragma unroll
        for (int off = 32; off; off >>= 1) m = fmaxf(m, __shfl_xor(m, off));
        const float ex = expf(noisy - m);
        float s = ex;
#pragma unroll
        for (int off = 32; off; off >>= 1) s += __shfl_xor(s, off);
        const float p = ex / s;

        float cur = p;
        int selrank = -1;
        float v[9];
#pragma unroll
        for (int j = 0; j < 9; ++j) {
            float bv = cur;
            int   bi = lane;
#pragma unroll
            for (int off = 32; off; off >>= 1) {
                const float ov = __shfl_xor(bv, off);
                const int   oi = __shfl_xor(bi, off);
                if (ov > bv || (ov == bv && oi < bi)) { bv = ov; bi = oi; }
            }
            v[j] = bv;
            if (lane == bi) { cur = -1.f; if (j < TK) selrank = j; }
        }

        float denom = 0.f;
#pragma unroll
        for (int j = 0; j < TK; ++j) denom += expf(v[j] - v[0]);
        const float gate = (selrank >= 0) ? (expf(p - v[0]) / denom) : 0.f;
        gates[(size_t)(rb + row) * EE + lane] = gate;

        const float thr_in  = v[8];
        const float thr_out = v[7];
        const bool  is_in   = noisy > thr_in;
        const float a = (clean - (is_in ? thr_in : thr_out)) / sd;
        loadAcc += 0.5f * (1.f + erff(a * 0.70710678118654752f));
    }

    red[w * 64 + lane] = loadAcc;
    __syncthreads();
    if (tid < 64) {
        const float s = red[tid] + red[64 + tid] + red[128 + tid] + red[192 + tid];
        atomicAdd(&load[tid], s);
    }
}

extern "C" void kernel_launch(void* const* d_in, const int* in_sizes, int n_in,
                              void* d_out, int out_size, void* d_ws, size_t ws_size,
                              hipStream_t stream)
{
    const float* x     = (const float*)d_in[0];
    const float* wg    = (const float*)d_in[1];
    const float* wn    = (const float*)d_in[2];
    const float* noise = (const float*)d_in[3];
    float* gates = (float*)d_out;
    float* load  = (float*)d_out + (size_t)BB * EE;
    char*  wsB   = (char*)d_ws;   // 2 MB

    hipMemsetAsync(load, 0, EE * sizeof(float), stream);
    hipLaunchKernelGGL(prep_w, dim3(DD / 64), dim3(256), 0, stream, wg, wn, wsB);
    hipLaunchKernelGGL(moe_mfma, dim3(BB / RT), dim3(256), 0, stream,
                       x, noise, wsB, gates, load);
}